// Round 1
// baseline (303.981 us; speedup 1.0000x reference)
//
#include <hip/hip_runtime.h>
#include <hip/hip_cooperative_groups.h>
#include <hip/hip_bf16.h>
#include <math.h>

#define N_NODES   50000
#define N_EDGES   1600000
#define IN_F      128
#define D_ATT     64
#define N_HEADS   8
#define D_HEAD    8
#define RSQRT8    0.35355339059327373f
#define EPS_SM    1e-16f
#define NEH       (N_EDGES * N_HEADS)      // 12.8M (edge,head)

// fused K2+K3 persistent grid
#define GRID_F    1024
#define THR_F     256
#define STRIDE_F  (GRID_F * THR_F)         // 262144 threads
#define ITEMS     49                       // ceil(NEH / STRIDE_F)

__device__ inline unsigned short f2bf(float v) {
    __hip_bfloat16 b = __float2bfloat16(v);
    return *(unsigned short*)&b;
}
__device__ inline float bflo(unsigned u) { return __uint_as_float(u << 16); }
__device__ inline float bfhi(unsigned u) { return __uint_as_float(u & 0xffff0000u); }

// ---------------------------------------------------------------------------
// K1: fused q/k/v projection, LDS-tiled SGEMM (64-node tile / block).
// Also zeroes the segment-sum table s (stream ordering guarantees s is zero
// before the edge kernel starts).
// q/k stored as bf16 rows [n*64 + j] (j = h*8+d) -> 128 B/node.
// v written f32 transposed to d_out[n*64 + d*8 + h].
// ---------------------------------------------------------------------------
__global__ __launch_bounds__(256) void k_proj(
        const float* __restrict__ x,
        const float* __restrict__ Wq, const float* __restrict__ bq,
        const float* __restrict__ Wk, const float* __restrict__ bk,
        const float* __restrict__ Wv, const float* __restrict__ bv,
        unsigned short* __restrict__ qp, unsigned short* __restrict__ kp,
        float* __restrict__ vout, float* __restrict__ s) {
    __shared__ float Xs[128][64];   // 32 KB
    __shared__ float Ws[128][64];   // 32 KB
    const int tid = threadIdx.x;
    const int n0  = blockIdx.x * 64;
    const int ln  = tid & 63;
    const int kb  = tid >> 6;

    // ---- zero segment-sum table (grid-stride; 400K elements) ----
    {
        int nthr = gridDim.x * 256;
        for (int i = blockIdx.x * 256 + tid; i < N_NODES * N_HEADS; i += nthr)
            s[i] = 0.0f;
    }

    {   // stage X tile (transposed)
        int n = n0 + ln;
        if (n < N_NODES) {
            const float4* xr = (const float4*)(x + (size_t)n * IN_F + kb * 32);
#pragma unroll
            for (int i = 0; i < 8; ++i) {
                float4 v = xr[i];
                int k = kb * 32 + i * 4;
                Xs[k + 0][ln] = v.x; Xs[k + 1][ln] = v.y;
                Xs[k + 2][ln] = v.z; Xs[k + 3][ln] = v.w;
            }
        } else {
#pragma unroll
            for (int i = 0; i < 8; ++i) {
                int k = kb * 32 + i * 4;
                Xs[k + 0][ln] = 0.f; Xs[k + 1][ln] = 0.f;
                Xs[k + 2][ln] = 0.f; Xs[k + 3][ln] = 0.f;
            }
        }
    }

    const int tx = tid & 15;        // node group
    const int ty = tid >> 4;        // feature group

    const float* Wlist[3] = {Wq, Wk, Wv};
    const float* blist[3] = {bq, bk, bv};

    for (int mm = 0; mm < 3; ++mm) {
        __syncthreads();
        {   // stage W tile (transposed)
            const float4* wr = (const float4*)(Wlist[mm] + (size_t)ln * IN_F + kb * 32);
#pragma unroll
            for (int i = 0; i < 8; ++i) {
                float4 v = wr[i];
                int k = kb * 32 + i * 4;
                Ws[k + 0][ln] = v.x; Ws[k + 1][ln] = v.y;
                Ws[k + 2][ln] = v.z; Ws[k + 3][ln] = v.w;
            }
        }
        __syncthreads();

        float acc[4][4] = {};
#pragma unroll 4
        for (int kk = 0; kk < 128; ++kk) {
            float4 a = *(const float4*)&Xs[kk][tx * 4];
            float4 b = *(const float4*)&Ws[kk][ty * 4];
            float xr[4] = {a.x, a.y, a.z, a.w};
            float wr[4] = {b.x, b.y, b.z, b.w};
#pragma unroll
            for (int i = 0; i < 4; ++i)
#pragma unroll
                for (int j = 0; j < 4; ++j)
                    acc[i][j] += xr[i] * wr[j];
        }

        float bj[4];
#pragma unroll
        for (int j = 0; j < 4; ++j) bj[j] = blist[mm][ty * 4 + j];

#pragma unroll
        for (int i = 0; i < 4; ++i) {
            int nn = n0 + tx * 4 + i;
            if (nn >= N_NODES) continue;
            if (mm < 2) {
                unsigned short* dstp = (mm == 0 ? qp : kp) + (size_t)nn * 64 + ty * 4;
                ushort4 o;
                o.x = f2bf(acc[i][0] + bj[0]);
                o.y = f2bf(acc[i][1] + bj[1]);
                o.z = f2bf(acc[i][2] + bj[2]);
                o.w = f2bf(acc[i][3] + bj[3]);
                *(ushort4*)dstp = o;
            } else {
#pragma unroll
                for (int j = 0; j < 4; ++j) {
                    int jj = ty * 4 + j;
                    vout[(size_t)nn * 64 + (jj & 7) * 8 + (jj >> 3)] =
                        acc[i][j] + bj[j];
                }
            }
        }
    }
}

// ---------------------------------------------------------------------------
// K2+K3 fused (cooperative): phase 1 computes prods + exp + segment-sum
// (identical access pattern to the proven 87 us k_prods_exp: 8 threads/edge,
// one 16 B bf16 fragment per lane).  exp(p) stays in registers across a
// grid-wide sync; phase 2 only re-reads e1 + the L2-resident sum table and
// writes att.  Saves k_norm's 51.2 MB prods re-read + 12.8M exp + a launch.
// ep[] is statically indexed via full unroll (runtime-indexed ext arrays go
// to scratch).  prods/att are streaming-only -> nontemporal stores keep L2
// for the q/k gathers.
// ---------------------------------------------------------------------------
__global__ __launch_bounds__(THR_F, 4) void k_fused(
        const int* __restrict__ e0, const int* __restrict__ e1,
        const float* __restrict__ ea,
        const unsigned short* __restrict__ qp,
        const unsigned short* __restrict__ kp,
        float* __restrict__ prods_out,
        float* __restrict__ s,
        float* __restrict__ att) {
    const int base = blockIdx.x * THR_F + threadIdx.x;
    float ep[ITEMS];

#pragma unroll
    for (int i = 0; i < ITEMS; ++i) {
        int t = base + i * STRIDE_F;
        if (t < NEH) {
            int e = t >> 3, h = t & 7;
            int src = e0[e];
            int dst = e1[e];
            float w = ea[e] * RSQRT8;
            uint4 qv = *(const uint4*)(qp + (size_t)src * 64 + h * 8);
            uint4 kv = *(const uint4*)(kp + (size_t)dst * 64 + h * 8);
            float dot = bflo(qv.x) * bflo(kv.x) + bfhi(qv.x) * bfhi(kv.x)
                      + bflo(qv.y) * bflo(kv.y) + bfhi(qv.y) * bfhi(kv.y)
                      + bflo(qv.z) * bflo(kv.z) + bfhi(qv.z) * bfhi(kv.z)
                      + bflo(qv.w) * bflo(kv.w) + bfhi(qv.w) * bfhi(kv.w);
            float p = dot * w;
            __builtin_nontemporal_store(p, &prods_out[t]);   // coalesced, never re-read
            float ev = __expf(p);
            ep[i] = ev;
            atomicAdd(&s[(size_t)dst * 8 + h], ev);          // device-scope, fire-and-forget
        } else {
            ep[i] = 0.0f;
        }
    }

    // all atomics device-visible after this (agent-scope acq_rel fence inside)
    cooperative_groups::this_grid().sync();

#pragma unroll
    for (int i = 0; i < ITEMS; ++i) {
        int t = base + i * STRIDE_F;
        if (t < NEH) {
            int e = t >> 3, h = t & 7;
            int dst = e1[e];
            float a = ep[i] / (s[(size_t)dst * 8 + h] + EPS_SM);
            __builtin_nontemporal_store(a, &att[t]);
        }
    }
}

// ---------------------------------------------------------------------------
// Fallback pair (current proven path) in case cooperative launch is not
// available / capacity check fails.
// ---------------------------------------------------------------------------
__global__ void k_prods_exp(const int* __restrict__ e0, const int* __restrict__ e1,
                            const float* __restrict__ ea,
                            const unsigned short* __restrict__ qp,
                            const unsigned short* __restrict__ kp,
                            float* __restrict__ prods_out,
                            float* __restrict__ s) {
    int t = blockIdx.x * blockDim.x + threadIdx.x;
    if (t >= NEH) return;
    int e = t >> 3, h = t & 7;
    int src = e0[e];
    int dst = e1[e];
    float w = ea[e] * RSQRT8;
    uint4 qv = *(const uint4*)(qp + (size_t)src * 64 + h * 8);
    uint4 kv = *(const uint4*)(kp + (size_t)dst * 64 + h * 8);
    float dot = bflo(qv.x) * bflo(kv.x) + bfhi(qv.x) * bfhi(kv.x)
              + bflo(qv.y) * bflo(kv.y) + bfhi(qv.y) * bfhi(kv.y)
              + bflo(qv.z) * bflo(kv.z) + bfhi(qv.z) * bfhi(kv.z)
              + bflo(qv.w) * bflo(kv.w) + bfhi(qv.w) * bfhi(kv.w);
    float p = dot * w;
    prods_out[t] = p;
    atomicAdd(&s[(size_t)dst * 8 + h], __expf(p));
}

__global__ void k_norm(const int* __restrict__ e1,
                       const float* __restrict__ prods,
                       float* __restrict__ att,
                       const float* __restrict__ s) {
    int t = blockIdx.x * blockDim.x + threadIdx.x;
    if (t >= NEH) return;
    int e = t >> 3, h = t & 7;
    int dst = e1[e];
    att[t] = __expf(prods[t]) / (s[(size_t)dst * 8 + h] + EPS_SM);
}

extern "C" void kernel_launch(void* const* d_in, const int* in_sizes, int n_in,
                              void* d_out, int out_size, void* d_ws, size_t ws_size,
                              hipStream_t stream) {
    const float* x  = (const float*)d_in[0];
    const float* Wq = (const float*)d_in[1];
    const float* bq = (const float*)d_in[2];
    const float* Wk = (const float*)d_in[3];
    const float* bk = (const float*)d_in[4];
    const float* Wv = (const float*)d_in[5];
    const float* bv = (const float*)d_in[6];
    const float* ea = (const float*)d_in[7];
    const int*   edge = (const int*)d_in[8];
    const int* e0 = edge;
    const int* e1 = edge + N_EDGES;

    float* out   = (float*)d_out;
    float* att   = out;                                  // (E, 8)
    float* vout  = att + (size_t)NEH;                    // (N, 8, 8)
    float* prods = vout + (size_t)N_NODES * D_ATT;       // (E, 8)

    unsigned short* qp = (unsigned short*)d_ws;          // (N, 64) bf16
    unsigned short* kp = qp + (size_t)N_NODES * D_ATT;   // (N, 64) bf16
    float* ssum = (float*)(kp + (size_t)N_NODES * D_ATT);// (N, 8) f32

    const int B = 256;
    int nTiles = (N_NODES + 63) / 64;
    k_proj<<<nTiles, 256, 0, stream>>>(x, Wq, bq, Wk, bk, Wv, bv,
                                       qp, kp, vout, ssum);

    // one-time capacity check for the cooperative fused kernel
    static int use_coop = -1;
    if (use_coop < 0) {
        int nb = 0;
        hipError_t err = hipOccupancyMaxActiveBlocksPerMultiprocessor(
                &nb, k_fused, THR_F, 0);
        // need 4 blocks/CU x 256 CUs (gfx950) >= GRID_F co-resident blocks
        use_coop = (err == hipSuccess && nb >= 4) ? 1 : 0;
    }

    bool launched = false;
    if (use_coop) {
        void* args[] = {(void*)&e0, (void*)&e1, (void*)&ea, (void*)&qp,
                        (void*)&kp, (void*)&prods, (void*)&ssum, (void*)&att};
        hipError_t err = hipLaunchCooperativeKernel(
                k_fused, dim3(GRID_F), dim3(THR_F), args, 0, stream);
        if (err == hipSuccess) launched = true;
        else use_coop = 0;   // permanent fallback
    }

    if (!launched) {
        int nEH = NEH;
        k_prods_exp<<<(nEH + B - 1) / B, B, 0, stream>>>(e0, e1, ea, qp, kp,
                                                         prods, ssum);
        k_norm<<<(nEH + B - 1) / B, B, 0, stream>>>(e1, prods, att, ssum);
    }
}